// Round 2
// baseline (50.956 us; speedup 1.0000x reference)
//
#include <hip/hip_runtime.h>

// Flash attention fwd, fp32 in/out, f16 MFMA compute, per-batch key masking.
// B=16, LQ=LK=2048, D=64. Swapped QK^T (S^T = K*Q) so softmax is lane-local;
// PV consumes P directly from S^T C-layout registers (slot-consistent with a
// matching Vt LDS read order) -> zero cross-lane shuffles in the main loop.

namespace {

constexpr int NB  = 16;
constexpr int SLQ = 2048;
constexpr int SLK = 2048;
constexpr int DH  = 64;
constexpr int KB  = 64;   // key tile
constexpr int QB  = 64;   // q rows per block (4 waves x 16)
constexpr int KST = 72;   // K lds row stride (halves) -> 144B, breaks 128B bank aliasing
constexpr int VST = 76;   // Vt lds row stride (halves) -> 152B, 8B-aligned for b64

typedef _Float16 half8  __attribute__((ext_vector_type(8)));
typedef _Float16 half4  __attribute__((ext_vector_type(4)));
typedef _Float16 half2t __attribute__((ext_vector_type(2)));
typedef float    f32x4  __attribute__((ext_vector_type(4)));

__device__ inline half2t pkrtz(float a, float b) {
    return __builtin_bit_cast(half2t, __builtin_amdgcn_cvt_pkrtz(a, b));
}

__global__ __launch_bounds__(256)
void attn_fwd(const float* __restrict__ qg, const float* __restrict__ kg,
              const float* __restrict__ vg, const int* __restrict__ vn,
              float* __restrict__ og)
{
    __shared__ _Float16 Kl[KB][KST];   // K tile, [key][d]
    __shared__ _Float16 Vt[DH][VST];   // V tile transposed, [d][key]

    const int t   = threadIdx.x;
    const int l   = t & 63;
    const int w   = t >> 6;     // wave id 0..3
    const int q15 = l & 15;     // q col within wave's 16 rows (C-layout col)
    const int g   = l >> 4;     // lane group 0..3

    const int bid = blockIdx.x;
    const int b   = bid & (NB - 1);   // batch fastest -> CUs get mixed valid_num
    const int qt  = bid >> 4;

    const int valid = vn[b];
    const int nkt   = (valid + KB - 1) / KB;   // skip fully-masked key tiles

    const int qrow = qt * QB + w * 16 + q15;

    // fold 1/sqrt(D)=1/8 and log2(e) into Q so scores are already in log2 units
    const float QS = 0.18033688011112042f;  // log2(e)/8

    // Q fragment (B-operand layout: col=q15, k(d)=8g+32s+j), kept in regs
    half8 qf[2];
    {
        const float* qp = qg + ((size_t)b * SLQ + qrow) * DH;
#pragma unroll
        for (int s = 0; s < 2; ++s) {
            const int d0 = 8 * g + 32 * s;
            f32x4 x = *(const f32x4*)(qp + d0);
            f32x4 y = *(const f32x4*)(qp + d0 + 4);
            half8 h;
#pragma unroll
            for (int i = 0; i < 4; ++i) {
                h[i]     = (_Float16)(x[i] * QS);
                h[i + 4] = (_Float16)(y[i] * QS);
            }
            qf[s] = h;
        }
    }

    // out^T accumulators: acc[mt][r] = out[q15][16*mt + 4*g + r]
    f32x4 acc[4];
#pragma unroll
    for (int i = 0; i < 4; ++i) acc[i] = f32x4{0.f, 0.f, 0.f, 0.f};

    float m    = -1e30f;
    float lsum = 0.f;

    const float* kbp = kg + (size_t)b * SLK * DH;
    const float* vbp = vg + (size_t)b * SLK * DH;

    for (int kt = 0; kt < nkt; ++kt) {
        __syncthreads();   // previous tile's LDS reads done before overwrite

        // ---- stage K tile: 256 threads, each 1 row-quarter (16 f32 -> 16 f16)
        {
            const int row = t >> 2;
            const int d0  = (t & 3) * 16;
            const float* kp = kbp + (size_t)(kt * KB + row) * DH + d0;
            f32x4 a0 = *(const f32x4*)(kp);
            f32x4 a1 = *(const f32x4*)(kp + 4);
            f32x4 a2 = *(const f32x4*)(kp + 8);
            f32x4 a3 = *(const f32x4*)(kp + 12);
            half8 h0, h1;
#pragma unroll
            for (int i = 0; i < 4; ++i) {
                h0[i]     = (_Float16)a0[i];
                h0[i + 4] = (_Float16)a1[i];
                h1[i]     = (_Float16)a2[i];
                h1[i + 4] = (_Float16)a3[i];
            }
            *(half8*)&Kl[row][d0]     = h0;
            *(half8*)&Kl[row][d0 + 8] = h1;
        }
        // ---- stage V transposed: thread owns keys {kk,kk+1} x 4 d's x 2 passes
        {
            const int kk = (t & 31) * 2;
            const int db = (t >> 5) * 4;
#pragma unroll
            for (int dd = 0; dd < 2; ++dd) {
                const int d0 = db + 32 * dd;
                const float* vp = vbp + (size_t)(kt * KB + kk) * DH + d0;
                f32x4 r0 = *(const f32x4*)(vp);
                f32x4 r1 = *(const f32x4*)(vp + DH);
#pragma unroll
                for (int i = 0; i < 4; ++i) {
                    // Vt[d][kk..kk+1] = {V[kk][d], V[kk+1][d]} ; 2-way-free banks
                    *(half2t*)&Vt[d0 + i][kk] = pkrtz(r0[i], r1[i]);
                }
            }
        }
        __syncthreads();

        // ---- QK^T (swapped): st[mt] C-layout: col=q15, row=key 16mt+4g+r
        f32x4 st[4];
#pragma unroll
        for (int mt = 0; mt < 4; ++mt) {
            f32x4 c = f32x4{0.f, 0.f, 0.f, 0.f};
#pragma unroll
            for (int s = 0; s < 2; ++s) {
                half8 a = *(const half8*)&Kl[16 * mt + q15][8 * g + 32 * s];
                c = __builtin_amdgcn_mfma_f32_16x16x32_f16(a, qf[s], c, 0, 0, 0);
            }
            st[mt] = c;
        }

        // ---- mask the (only) partial boundary tile
        const int krem = valid - kt * KB;
        if (krem < KB) {
#pragma unroll
            for (int mt = 0; mt < 4; ++mt)
#pragma unroll
                for (int r = 0; r < 4; ++r)
                    if (16 * mt + 4 * g + r >= krem) st[mt][r] = -1e30f;
        }

        // ---- online softmax (scores already in log2 units)
        float tmax = -1e30f;
#pragma unroll
        for (int mt = 0; mt < 4; ++mt)
#pragma unroll
            for (int r = 0; r < 4; ++r) tmax = fmaxf(tmax, st[mt][r]);
        tmax = fmaxf(tmax, __shfl_xor(tmax, 16));
        tmax = fmaxf(tmax, __shfl_xor(tmax, 32));

        const float mn = fmaxf(m, tmax);
        const float sc = __builtin_amdgcn_exp2f(m - mn);

        float p[4][4];
        float ps = 0.f;
#pragma unroll
        for (int mt = 0; mt < 4; ++mt)
#pragma unroll
            for (int r = 0; r < 4; ++r) {
                const float e = __builtin_amdgcn_exp2f(st[mt][r] - mn);
                p[mt][r] = e;
                ps += e;
            }
        ps += __shfl_xor(ps, 16);
        ps += __shfl_xor(ps, 32);
        lsum = lsum * sc + ps;
        m = mn;
#pragma unroll
        for (int mt = 0; mt < 4; ++mt) acc[mt] *= sc;

        // ---- pack P to f16 (stays in registers; key id carried by slot order)
        half2t pk[4][2];
#pragma unroll
        for (int mt = 0; mt < 4; ++mt)
#pragma unroll
            for (int rr = 0; rr < 2; ++rr)
                pk[mt][rr] = pkrtz(p[mt][2 * rr], p[mt][2 * rr + 1]);

        // ---- PV: out^T += Vt * P^T. B-slot (g,j) carries key 32s+16(j>>2)+4g+(j&3);
        //      A (Vt) is read in exactly that key order -> slot-consistent, no shuffles.
#pragma unroll
        for (int s = 0; s < 2; ++s) {
            union { half2t h2[4]; half8 v; } bf;
            bf.h2[0] = pk[2 * s][0];
            bf.h2[1] = pk[2 * s][1];
            bf.h2[2] = pk[2 * s + 1][0];
            bf.h2[3] = pk[2 * s + 1][1];
#pragma unroll
            for (int mt = 0; mt < 4; ++mt) {
                union { half4 h4[2]; half8 v; } af;
                af.h4[0] = *(const half4*)&Vt[16 * mt + q15][32 * s + 4 * g];
                af.h4[1] = *(const half4*)&Vt[16 * mt + q15][32 * s + 16 + 4 * g];
                acc[mt] = __builtin_amdgcn_mfma_f32_16x16x32_f16(af.v, bf.v, acc[mt], 0, 0, 0);
            }
        }
    }

    // ---- epilogue: divide by softmax denom, store float4 per d-tile
    const float inv = 1.0f / lsum;
    float* op = og + ((size_t)b * SLQ + qrow) * DH;
#pragma unroll
    for (int mt = 0; mt < 4; ++mt) {
        f32x4 o;
#pragma unroll
        for (int r = 0; r < 4; ++r) o[r] = acc[mt][r] * inv;
        *(f32x4*)(op + 16 * mt + 4 * g) = o;
    }
}

} // namespace

extern "C" void kernel_launch(void* const* d_in, const int* in_sizes, int n_in,
                              void* d_out, int out_size, void* d_ws, size_t ws_size,
                              hipStream_t stream)
{
    const float* q    = (const float*)d_in[0];
    const float* k    = (const float*)d_in[1];
    const float* v    = (const float*)d_in[2];
    const int*   vnum = (const int*)d_in[3];
    float* out = (float*)d_out;

    dim3 grid(NB * (SLQ / QB));   // 512 blocks, batch-major fastest
    dim3 block(256);
    attn_fwd<<<grid, block, 0, stream>>>(q, k, v, vnum, out);
}